// Round 1
// baseline (349.426 us; speedup 1.0000x reference)
//
#include <hip/hip_runtime.h>
#include <cstdint>
#include <cstddef>

typedef unsigned short u16;
typedef __bf16 bf16x8 __attribute__((ext_vector_type(8)));
typedef float floatx4 __attribute__((ext_vector_type(4)));

#define NPTS 4096
#define MGRD 4096
#define DDIM 8

// round-to-nearest-even fp32 -> bf16 (values here are finite, no NaN concern)
static __device__ __forceinline__ u16 f2bf(float f) {
    uint32_t u = __float_as_uint(f);
    u += 0x7fffu + ((u >> 16) & 1u);
    return (u16)(u >> 16);
}

// ---------------- P1: k_star[n][k] = exp(-sum_d |x[n,d]-g[k,d]|/ls[d]) -> bf16 ----------------
// grid (2, 4096), block 256. Each thread computes 8 consecutive k for one n (16B store).
__global__ __launch_bounds__(256) void kstar_kernel(
    const float* __restrict__ x, const float* __restrict__ g,
    const float* __restrict__ ls, u16* __restrict__ out)
{
    const int n  = blockIdx.y;
    const int kc = blockIdx.x * 256 + threadIdx.x;   // 0..511
    const int k0 = kc * 8;

    float xr[DDIM], il[DDIM];
#pragma unroll
    for (int d = 0; d < DDIM; ++d) {
        xr[d] = x[n * DDIM + d];
        il[d] = 1.0f / ls[d];
    }

    alignas(16) u16 res[8];
#pragma unroll
    for (int j = 0; j < 8; ++j) {
        const float* gr = g + (size_t)(k0 + j) * DDIM;
        float s = 0.0f;
#pragma unroll
        for (int d = 0; d < DDIM; ++d)
            s += fabsf(xr[d] - gr[d]) * il[d];
        res[j] = f2bf(__expf(-s));
    }
    *reinterpret_cast<uint4*>(out + (size_t)n * MGRD + k0) = *reinterpret_cast<const uint4*>(res);
}

// ---------------- P2: Bt[m][k] = (bf16)chol_inv[k][m]  (transpose + convert) ----------------
// grid (64, 64), block 256, 64x64 tiles via padded LDS.
__global__ __launch_bounds__(256) void tconv_kernel(
    const float* __restrict__ B, u16* __restrict__ Bt)
{
    __shared__ float tile[64][65];
    const int k0 = blockIdx.y * 64;   // source rows (k)
    const int m0 = blockIdx.x * 64;   // source cols (m)
    const int tid = threadIdx.x;

#pragma unroll
    for (int r = 0; r < 4; ++r) {
        int c   = r * 256 + tid;      // 0..1023 float4 chunks
        int row = c >> 4;
        int col = (c & 15) * 4;
        const float4 v = *reinterpret_cast<const float4*>(&B[(size_t)(k0 + row) * MGRD + m0 + col]);
        tile[row][col + 0] = v.x; tile[row][col + 1] = v.y;
        tile[row][col + 2] = v.z; tile[row][col + 3] = v.w;
    }
    __syncthreads();

#pragma unroll
    for (int r = 0; r < 2; ++r) {
        int c  = r * 256 + tid;       // 0..511 bf16x8 chunks
        int mr = c >> 3;
        int kc = (c & 7) * 8;
        alignas(16) u16 tmp[8];
#pragma unroll
        for (int j = 0; j < 8; ++j)
            tmp[j] = f2bf(tile[kc + j][mr]);
        *reinterpret_cast<uint4*>(&Bt[(size_t)(m0 + mr) * MGRD + k0 + kc]) =
            *reinterpret_cast<const uint4*>(tmp);
    }
}

// ---------------- G: C[n][m] = sum_k A[n][k] * Bt[m][k], bf16 MFMA, fp32 out ----------------
// m97 structure: 128x128 tile, BK=64, 256 threads (4 waves, 2x2 wave grid, 4x4 16x16 frags each),
// global_load_lds width-16 staging.
__global__ __launch_bounds__(256, 3) void gemm_bt_kernel(
    const u16* __restrict__ A,    // [4096][4096] bf16 (n-major, k contiguous)
    const u16* __restrict__ Bt,   // [4096][4096] bf16 (m-major, k contiguous)
    float* __restrict__ C)        // [4096][4096] fp32
{
    __shared__ u16 sA[128 * 64] __attribute__((aligned(16)));
    __shared__ u16 sB[128 * 64] __attribute__((aligned(16)));

    const int tid   = threadIdx.x;
    const int lane  = tid & 63;
    const int w     = tid >> 6;
    const int wbase = w * 64;           // wave's staging chunk base within a round
    const int wm    = (w >> 1) * 64;    // wave n-offset in tile
    const int wn    = (w & 1) * 64;     // wave m-offset in tile
    const int bn0   = blockIdx.y * 128;
    const int bm0   = blockIdx.x * 128;
    const int lrow  = lane & 15;
    const int lhi   = lane >> 4;        // 0..3

    floatx4 acc[4][4];
#pragma unroll
    for (int i = 0; i < 4; ++i)
#pragma unroll
        for (int j = 0; j < 4; ++j)
            acc[i][j] = (floatx4)0.0f;

    for (int k0 = 0; k0 < 4096; k0 += 64) {
        // Stage A-tile [128 n][64 k] and Bt-tile [128 m][64 k], bf16, 16KB each.
        // chunk c = r*256 + tid covers row c>>3, k ((c&7)*8..+8). LDS dest is
        // wave-uniform base + lane*16 (global_load_lds constraint) == chunk order.
#pragma unroll
        for (int r = 0; r < 4; ++r) {
            int c   = r * 256 + tid;
            int row = c >> 3;
            int kc  = (c & 7) * 8;
            const u16* ga = A  + (size_t)(bn0 + row) * 4096 + k0 + kc;
            const u16* gb = Bt + (size_t)(bm0 + row) * 4096 + k0 + kc;
            __builtin_amdgcn_global_load_lds(
                (const __attribute__((address_space(1))) void*)ga,
                (__attribute__((address_space(3))) void*)(sA + (size_t)(r * 256 + wbase) * 8),
                16, 0, 0);
            __builtin_amdgcn_global_load_lds(
                (const __attribute__((address_space(1))) void*)gb,
                (__attribute__((address_space(3))) void*)(sB + (size_t)(r * 256 + wbase) * 8),
                16, 0, 0);
        }
        __syncthreads();

#pragma unroll
        for (int s = 0; s < 2; ++s) {
            bf16x8 af[4], bfr[4];
#pragma unroll
            for (int i = 0; i < 4; ++i)
                af[i] = *reinterpret_cast<const bf16x8*>(
                    &sA[(size_t)(wm + i * 16 + lrow) * 64 + s * 32 + lhi * 8]);
#pragma unroll
            for (int j = 0; j < 4; ++j)
                bfr[j] = *reinterpret_cast<const bf16x8*>(
                    &sB[(size_t)(wn + j * 16 + lrow) * 64 + s * 32 + lhi * 8]);
#pragma unroll
            for (int i = 0; i < 4; ++i)
#pragma unroll
                for (int j = 0; j < 4; ++j)
                    acc[i][j] = __builtin_amdgcn_mfma_f32_16x16x32_bf16(
                        af[i], bfr[j], acc[i][j], 0, 0, 0);
        }
        __syncthreads();
    }

    // Epilogue: C/D layout col=lane&15 (m), row=(lane>>4)*4+reg (n)  [m89-verified]
#pragma unroll
    for (int i = 0; i < 4; ++i) {
        int rown = bn0 + wm + i * 16 + lhi * 4;
#pragma unroll
        for (int j = 0; j < 4; ++j) {
            int colm = bm0 + wn + j * 16 + lrow;
            float* cp = C + (size_t)rown * 4096 + colm;
#pragma unroll
            for (int rr = 0; rr < 4; ++rr)
                cp[(size_t)rr * 4096] = acc[i][j][rr];
        }
    }
}

extern "C" void kernel_launch(void* const* d_in, const int* in_sizes, int n_in,
                              void* d_out, int out_size, void* d_ws, size_t ws_size,
                              hipStream_t stream)
{
    const float* x    = (const float*)d_in[0];   // [4096,8]
    const float* grid = (const float*)d_in[1];   // [4096,8]
    const float* ci   = (const float*)d_in[2];   // [4096,4096]
    const float* ls   = (const float*)d_in[3];   // [8]
    float* out = (float*)d_out;                  // [4096,4096] fp32

    u16* wsA  = (u16*)d_ws;                            // k_star bf16, 33.5 MB
    u16* wsBt = (u16*)d_ws + (size_t)MGRD * MGRD;      // chol_inv^T bf16, 33.5 MB

    kstar_kernel<<<dim3(2, NPTS), 256, 0, stream>>>(x, grid, ls, wsA);
    tconv_kernel<<<dim3(64, 64), 256, 0, stream>>>(ci, wsBt);
    gemm_bt_kernel<<<dim3(32, 32), 256, 0, stream>>>(wsA, wsBt, out);
}

// Round 2
// 296.583 us; speedup vs baseline: 1.1782x; 1.1782x over previous
//
#include <hip/hip_runtime.h>
#include <cstdint>
#include <cstddef>

typedef unsigned short u16;
typedef __bf16 bf16x8 __attribute__((ext_vector_type(8)));
typedef float floatx4 __attribute__((ext_vector_type(4)));

#define NPTS 4096
#define MGRD 4096
#define DDIM 8

// round-to-nearest-even fp32 -> bf16
static __device__ __forceinline__ u16 f2bf(float f) {
    uint32_t u = __float_as_uint(f);
    u += 0x7fffu + ((u >> 16) & 1u);
    return (u16)(u >> 16);
}

// ---------------- Fused prep: k_star (blocks 0..8191) + tril transpose (blocks 8192..) -------
// kstar: A[n][k] = bf16( exp(-sum_d |x[n,d]-g[k,d]|/ls[d]) ), n-major k-contiguous.
// tconv: Bt[m][k] = bf16( chol_inv[k][m] ), only block-lower-triangular tiles (GEMM reads
//        Bt[m][k] only for k >= floor(m/128)*128; tile keep-condition by >= (bx & ~1)).
__global__ __launch_bounds__(256) void prep_kernel(
    const float* __restrict__ x, const float* __restrict__ g,
    const float* __restrict__ ls, const float* __restrict__ B,
    u16* __restrict__ A, u16* __restrict__ Bt)
{
    __shared__ float tile[64][65];
    const int bid = blockIdx.x;
    const int tid = threadIdx.x;

    if (bid < 2 * NPTS) {
        // ---- kstar ----
        const int n  = bid >> 1;
        const int k0 = ((bid & 1) * 256 + tid) * 8;   // 8 consecutive k per thread

        float xr[DDIM], il[DDIM];
#pragma unroll
        for (int d = 0; d < DDIM; ++d) {
            xr[d] = x[n * DDIM + d];
            il[d] = 1.0f / ls[d];
        }

        alignas(16) u16 res[8];
#pragma unroll
        for (int j = 0; j < 8; ++j) {
            const float4 g0 = *reinterpret_cast<const float4*>(g + (size_t)(k0 + j) * DDIM);
            const float4 g1 = *reinterpret_cast<const float4*>(g + (size_t)(k0 + j) * DDIM + 4);
            float s = fabsf(xr[0] - g0.x) * il[0] + fabsf(xr[1] - g0.y) * il[1]
                    + fabsf(xr[2] - g0.z) * il[2] + fabsf(xr[3] - g0.w) * il[3]
                    + fabsf(xr[4] - g1.x) * il[4] + fabsf(xr[5] - g1.y) * il[5]
                    + fabsf(xr[6] - g1.z) * il[6] + fabsf(xr[7] - g1.w) * il[7];
            res[j] = f2bf(__expf(-s));
        }
        *reinterpret_cast<uint4*>(A + (size_t)n * MGRD + k0) = *reinterpret_cast<const uint4*>(res);
    } else {
        // ---- transpose + convert (block-lower-triangular tiles only) ----
        const int id = bid - 2 * NPTS;
        const int bx = id & 63;          // m-tile
        const int by = id >> 6;          // k-tile
        if (by < (bx & ~1)) return;      // tile never read by triangular GEMM
        const int k0 = by * 64;
        const int m0 = bx * 64;

#pragma unroll
        for (int r = 0; r < 4; ++r) {
            int c   = r * 256 + tid;
            int row = c >> 4;
            int col = (c & 15) * 4;
            const float4 v = *reinterpret_cast<const float4*>(&B[(size_t)(k0 + row) * MGRD + m0 + col]);
            tile[row][col + 0] = v.x; tile[row][col + 1] = v.y;
            tile[row][col + 2] = v.z; tile[row][col + 3] = v.w;
        }
        __syncthreads();

#pragma unroll
        for (int r = 0; r < 2; ++r) {
            int c  = r * 256 + tid;
            int mr = c >> 3;
            int kc = (c & 7) * 8;
            alignas(16) u16 tmp[8];
#pragma unroll
            for (int j = 0; j < 8; ++j)
                tmp[j] = f2bf(tile[kc + j][mr]);
            *reinterpret_cast<uint4*>(&Bt[(size_t)(m0 + mr) * MGRD + k0 + kc]) =
                *reinterpret_cast<const uint4*>(tmp);
        }
    }
}

// ---------------- G: C[n][m] = sum_{k>=bm0} A[n][k] * Bt[m][k], bf16 MFMA, fp32 out --------
// m97 structure + XOR-swizzled LDS (16B-chunk index ^ (row&7)) to spread b128 fragment
// reads uniformly over all 32 banks (row stride is exactly 32 banks, so unswizzled reads
// concentrate 16 lanes on one 4-bank group -> 5e7 conflict cycles measured in R1).
// Triangular: chol_inv is tril, so K starts at bm0 (earlier Bt tiles are exact zeros).
__global__ __launch_bounds__(256, 3) void gemm_bt_kernel(
    const u16* __restrict__ A,    // [4096][4096] bf16 (n-major, k contiguous)
    const u16* __restrict__ Bt,   // [4096][4096] bf16 (m-major, k contiguous)
    float* __restrict__ C)        // [4096][4096] fp32
{
    __shared__ u16 sA[128 * 64] __attribute__((aligned(16)));
    __shared__ u16 sB[128 * 64] __attribute__((aligned(16)));

    const int tid   = threadIdx.x;
    const int lane  = tid & 63;
    const int w     = tid >> 6;
    const int wbase = w * 64;           // wave's staging chunk base within a round
    const int wm    = (w >> 1) * 64;    // wave n-offset in tile
    const int wn    = (w & 1) * 64;     // wave m-offset in tile
    const int bn0   = blockIdx.y * 128;
    const int bm0   = blockIdx.x * 128;
    const int lrow  = lane & 15;
    const int lhi   = lane >> 4;        // 0..3
    const int r7    = lrow & 7;         // read-side swizzle key (row&7 == lrow&7 here)

    floatx4 acc[4][4];
#pragma unroll
    for (int i = 0; i < 4; ++i)
#pragma unroll
        for (int j = 0; j < 4; ++j)
            acc[i][j] = (floatx4)0.0f;

    for (int k0 = bm0; k0 < 4096; k0 += 64) {
        // Stage A-tile [128 n][64 k] and Bt-tile [128 m][64 k]. Slot c = r*256+tid maps to
        // (row = c>>3, swizzled 16B-chunk = c&7); the data placed there is global chunk
        // (c&7) ^ (row&7) -- the LDS dest stays wave-order contiguous as global_load_lds
        // requires, while the *source* address carries the swizzle.
#pragma unroll
        for (int r = 0; r < 4; ++r) {
            int c   = r * 256 + tid;
            int row = c >> 3;
            int kc  = ((c ^ (c >> 3)) & 7) * 8;
            const u16* ga = A  + (size_t)(bn0 + row) * 4096 + k0 + kc;
            const u16* gb = Bt + (size_t)(bm0 + row) * 4096 + k0 + kc;
            __builtin_amdgcn_global_load_lds(
                (const __attribute__((address_space(1))) void*)ga,
                (__attribute__((address_space(3))) void*)(sA + (size_t)(r * 256 + wbase) * 8),
                16, 0, 0);
            __builtin_amdgcn_global_load_lds(
                (const __attribute__((address_space(1))) void*)gb,
                (__attribute__((address_space(3))) void*)(sB + (size_t)(r * 256 + wbase) * 8),
                16, 0, 0);
        }
        __syncthreads();

#pragma unroll
        for (int s = 0; s < 2; ++s) {
            const int sw = ((s * 4 + lhi) ^ r7) * 8;   // un-swizzled fragment chunk
            bf16x8 af[4], bfr[4];
#pragma unroll
            for (int i = 0; i < 4; ++i)
                af[i] = *reinterpret_cast<const bf16x8*>(
                    &sA[(size_t)(wm + i * 16 + lrow) * 64 + sw]);
#pragma unroll
            for (int j = 0; j < 4; ++j)
                bfr[j] = *reinterpret_cast<const bf16x8*>(
                    &sB[(size_t)(wn + j * 16 + lrow) * 64 + sw]);
#pragma unroll
            for (int i = 0; i < 4; ++i)
#pragma unroll
                for (int j = 0; j < 4; ++j)
                    acc[i][j] = __builtin_amdgcn_mfma_f32_16x16x32_bf16(
                        af[i], bfr[j], acc[i][j], 0, 0, 0);
        }
        __syncthreads();
    }

    // Epilogue: C/D layout col=lane&15 (m), row=(lane>>4)*4+reg (n)  [m89-verified]
#pragma unroll
    for (int i = 0; i < 4; ++i) {
        int rown = bn0 + wm + i * 16 + lhi * 4;
#pragma unroll
        for (int j = 0; j < 4; ++j) {
            int colm = bm0 + wn + j * 16 + lrow;
            float* cp = C + (size_t)rown * 4096 + colm;
#pragma unroll
            for (int rr = 0; rr < 4; ++rr)
                cp[(size_t)rr * 4096] = acc[i][j][rr];
        }
    }
}

extern "C" void kernel_launch(void* const* d_in, const int* in_sizes, int n_in,
                              void* d_out, int out_size, void* d_ws, size_t ws_size,
                              hipStream_t stream)
{
    const float* x    = (const float*)d_in[0];   // [4096,8]
    const float* grid = (const float*)d_in[1];   // [4096,8]
    const float* ci   = (const float*)d_in[2];   // [4096,4096]
    const float* ls   = (const float*)d_in[3];   // [8]
    float* out = (float*)d_out;                  // [4096,4096] fp32

    u16* wsA  = (u16*)d_ws;                            // k_star bf16, 33.5 MB
    u16* wsBt = (u16*)d_ws + (size_t)MGRD * MGRD;      // chol_inv^T bf16, 33.5 MB

    prep_kernel<<<dim3(2 * NPTS + 64 * 64), 256, 0, stream>>>(x, grid, ls, ci, wsA, wsBt);
    gemm_bt_kernel<<<dim3(32, 32), 256, 0, stream>>>(wsA, wsBt, out);
}

// Round 3
// 276.020 us; speedup vs baseline: 1.2659x; 1.0745x over previous
//
#include <hip/hip_runtime.h>
#include <cstdint>
#include <cstddef>

typedef unsigned short u16;
typedef __bf16 bf16x8 __attribute__((ext_vector_type(8)));
typedef float floatx4 __attribute__((ext_vector_type(4)));

#define NPTS 4096
#define MGRD 4096
#define DDIM 8

// round-to-nearest-even fp32 -> bf16
static __device__ __forceinline__ u16 f2bf(float f) {
    uint32_t u = __float_as_uint(f);
    u += 0x7fffu + ((u >> 16) & 1u);
    return (u16)(u >> 16);
}

// ---------------- Fused prep: k_star (blocks 0..8191) + tril transpose (blocks 8192..) -------
// kstar: A[n][k] = bf16( exp(-sum_d |x[n,d]-g[k,d]|/ls[d]) ), n-major k-contiguous.
// tconv: Bt[m][k] = bf16( chol_inv[k][m] ), only block-lower-triangular tiles (GEMM reads
//        Bt[m][k] only for k >= floor(m/128)*128; tile keep-condition by >= (bx & ~1)).
__global__ __launch_bounds__(256) void prep_kernel(
    const float* __restrict__ x, const float* __restrict__ g,
    const float* __restrict__ ls, const float* __restrict__ B,
    u16* __restrict__ A, u16* __restrict__ Bt)
{
    __shared__ float tile[64][65];
    const int bid = blockIdx.x;
    const int tid = threadIdx.x;

    if (bid < 2 * NPTS) {
        // ---- kstar ----
        const int n  = bid >> 1;
        const int k0 = ((bid & 1) * 256 + tid) * 8;   // 8 consecutive k per thread

        float xr[DDIM], il[DDIM];
#pragma unroll
        for (int d = 0; d < DDIM; ++d) {
            xr[d] = x[n * DDIM + d];
            il[d] = 1.0f / ls[d];
        }

        alignas(16) u16 res[8];
#pragma unroll
        for (int j = 0; j < 8; ++j) {
            const float4 g0 = *reinterpret_cast<const float4*>(g + (size_t)(k0 + j) * DDIM);
            const float4 g1 = *reinterpret_cast<const float4*>(g + (size_t)(k0 + j) * DDIM + 4);
            float s = fabsf(xr[0] - g0.x) * il[0] + fabsf(xr[1] - g0.y) * il[1]
                    + fabsf(xr[2] - g0.z) * il[2] + fabsf(xr[3] - g0.w) * il[3]
                    + fabsf(xr[4] - g1.x) * il[4] + fabsf(xr[5] - g1.y) * il[5]
                    + fabsf(xr[6] - g1.z) * il[6] + fabsf(xr[7] - g1.w) * il[7];
            res[j] = f2bf(__expf(-s));
        }
        *reinterpret_cast<uint4*>(A + (size_t)n * MGRD + k0) = *reinterpret_cast<const uint4*>(res);
    } else {
        // ---- transpose + convert (block-lower-triangular tiles only) ----
        const int id = bid - 2 * NPTS;
        const int bx = id & 63;          // m-tile
        const int by = id >> 6;          // k-tile
        if (by < (bx & ~1)) return;      // tile never read by triangular GEMM
        const int k0 = by * 64;
        const int m0 = bx * 64;

#pragma unroll
        for (int r = 0; r < 4; ++r) {
            int c   = r * 256 + tid;
            int row = c >> 4;
            int col = (c & 15) * 4;
            const float4 v = *reinterpret_cast<const float4*>(&B[(size_t)(k0 + row) * MGRD + m0 + col]);
            tile[row][col + 0] = v.x; tile[row][col + 1] = v.y;
            tile[row][col + 2] = v.z; tile[row][col + 3] = v.w;
        }
        __syncthreads();

#pragma unroll
        for (int r = 0; r < 2; ++r) {
            int c  = r * 256 + tid;
            int mr = c >> 3;
            int kc = (c & 7) * 8;
            alignas(16) u16 tmp[8];
#pragma unroll
            for (int j = 0; j < 8; ++j)
                tmp[j] = f2bf(tile[kc + j][mr]);
            *reinterpret_cast<uint4*>(&Bt[(size_t)(m0 + mr) * MGRD + k0 + kc]) =
                *reinterpret_cast<const uint4*>(tmp);
        }
    }
}

// ---------------- G: C[n][m] = sum_{k>=bm0} A[n][k] * Bt[m][k], bf16 MFMA, fp32 out --------
// m97 structure + XOR-swizzled LDS (conflict-free, verified 0 in R2) + triangular K.
// K iterates DOWNWARD (4032 -> bm0): every block's range contains the last tile, so all
// 1024 blocks (all resident, ~4/CU) start on the SAME k-tile and march in lockstep,
// retiring as they pass their own bm0. This restores the cross-block L2 slice-sharing
// that R1 had (FETCH 174 MB) and R2's phase-scattered forward loop destroyed (290 MB).
__global__ __launch_bounds__(256, 3) void gemm_bt_kernel(
    const u16* __restrict__ A,    // [4096][4096] bf16 (n-major, k contiguous)
    const u16* __restrict__ Bt,   // [4096][4096] bf16 (m-major, k contiguous)
    float* __restrict__ C)        // [4096][4096] fp32
{
    __shared__ u16 sA[128 * 64] __attribute__((aligned(16)));
    __shared__ u16 sB[128 * 64] __attribute__((aligned(16)));

    const int tid   = threadIdx.x;
    const int lane  = tid & 63;
    const int w     = tid >> 6;
    const int wbase = w * 64;           // wave's staging chunk base within a round
    const int wm    = (w >> 1) * 64;    // wave n-offset in tile
    const int wn    = (w & 1) * 64;     // wave m-offset in tile
    const int bn0   = blockIdx.y * 128;
    const int bm0   = blockIdx.x * 128;
    const int lrow  = lane & 15;
    const int lhi   = lane >> 4;        // 0..3
    const int r7    = lrow & 7;         // read-side swizzle key (row&7 == lrow&7 here)

    floatx4 acc[4][4];
#pragma unroll
    for (int i = 0; i < 4; ++i)
#pragma unroll
        for (int j = 0; j < 4; ++j)
            acc[i][j] = (floatx4)0.0f;

    for (int k0 = 4096 - 64; k0 >= bm0; k0 -= 64) {
        // Stage A-tile [128 n][64 k] and Bt-tile [128 m][64 k]. Slot c = r*256+tid maps to
        // (row = c>>3, swizzled 16B-chunk = c&7); the data placed there is global chunk
        // (c&7) ^ (row&7) -- LDS dest stays wave-order contiguous (global_load_lds
        // requirement); the *source* address carries the swizzle.
#pragma unroll
        for (int r = 0; r < 4; ++r) {
            int c   = r * 256 + tid;
            int row = c >> 3;
            int kc  = ((c ^ (c >> 3)) & 7) * 8;
            const u16* ga = A  + (size_t)(bn0 + row) * 4096 + k0 + kc;
            const u16* gb = Bt + (size_t)(bm0 + row) * 4096 + k0 + kc;
            __builtin_amdgcn_global_load_lds(
                (const __attribute__((address_space(1))) void*)ga,
                (__attribute__((address_space(3))) void*)(sA + (size_t)(r * 256 + wbase) * 8),
                16, 0, 0);
            __builtin_amdgcn_global_load_lds(
                (const __attribute__((address_space(1))) void*)gb,
                (__attribute__((address_space(3))) void*)(sB + (size_t)(r * 256 + wbase) * 8),
                16, 0, 0);
        }
        __syncthreads();

#pragma unroll
        for (int s = 0; s < 2; ++s) {
            const int sw = ((s * 4 + lhi) ^ r7) * 8;   // un-swizzled fragment chunk
            bf16x8 af[4], bfr[4];
#pragma unroll
            for (int i = 0; i < 4; ++i)
                af[i] = *reinterpret_cast<const bf16x8*>(
                    &sA[(size_t)(wm + i * 16 + lrow) * 64 + sw]);
#pragma unroll
            for (int j = 0; j < 4; ++j)
                bfr[j] = *reinterpret_cast<const bf16x8*>(
                    &sB[(size_t)(wn + j * 16 + lrow) * 64 + sw]);
#pragma unroll
            for (int i = 0; i < 4; ++i)
#pragma unroll
                for (int j = 0; j < 4; ++j)
                    acc[i][j] = __builtin_amdgcn_mfma_f32_16x16x32_bf16(
                        af[i], bfr[j], acc[i][j], 0, 0, 0);
        }
        __syncthreads();
    }

    // Epilogue: C/D layout col=lane&15 (m), row=(lane>>4)*4+reg (n)  [m89-verified]
#pragma unroll
    for (int i = 0; i < 4; ++i) {
        int rown = bn0 + wm + i * 16 + lhi * 4;
#pragma unroll
        for (int j = 0; j < 4; ++j) {
            int colm = bm0 + wn + j * 16 + lrow;
            float* cp = C + (size_t)rown * 4096 + colm;
#pragma unroll
            for (int rr = 0; rr < 4; ++rr)
                cp[(size_t)rr * 4096] = acc[i][j][rr];
        }
    }
}

extern "C" void kernel_launch(void* const* d_in, const int* in_sizes, int n_in,
                              void* d_out, int out_size, void* d_ws, size_t ws_size,
                              hipStream_t stream)
{
    const float* x    = (const float*)d_in[0];   // [4096,8]
    const float* grid = (const float*)d_in[1];   // [4096,8]
    const float* ci   = (const float*)d_in[2];   // [4096,4096]
    const float* ls   = (const float*)d_in[3];   // [8]
    float* out = (float*)d_out;                  // [4096,4096] fp32

    u16* wsA  = (u16*)d_ws;                            // k_star bf16, 33.5 MB
    u16* wsBt = (u16*)d_ws + (size_t)MGRD * MGRD;      // chol_inv^T bf16, 33.5 MB

    prep_kernel<<<dim3(2 * NPTS + 64 * 64), 256, 0, stream>>>(x, grid, ls, ci, wsA, wsBt);
    gemm_bt_kernel<<<dim3(32, 32), 256, 0, stream>>>(wsA, wsBt, out);
}

// Round 4
// 251.908 us; speedup vs baseline: 1.3871x; 1.0957x over previous
//
#include <hip/hip_runtime.h>
#include <cstdint>
#include <cstddef>

typedef unsigned short u16;
typedef __bf16 bf16x8 __attribute__((ext_vector_type(8)));
typedef float floatx4 __attribute__((ext_vector_type(4)));

#define NPTS 4096
#define MGRD 4096
#define DDIM 8

// round-to-nearest-even fp32 -> bf16
static __device__ __forceinline__ u16 f2bf(float f) {
    uint32_t u = __float_as_uint(f);
    u += 0x7fffu + ((u >> 16) & 1u);
    return (u16)(u >> 16);
}

// ---------------- Fused prep: k_star (blocks 0..8191) + tril transpose (blocks 8192..) -------
// kstar: A[n][k] = bf16( exp(-sum_d |x[n,d]-g[k,d]|/ls[d]) ), n-major k-contiguous.
// tconv: Bt[m][k] = bf16( chol_inv[k][m] ), only block-lower-triangular tiles (GEMM reads
//        Bt[m][k] only for k >= floor(m/128)*128; tile keep-condition by >= (bx & ~1)).
__global__ __launch_bounds__(256) void prep_kernel(
    const float* __restrict__ x, const float* __restrict__ g,
    const float* __restrict__ ls, const float* __restrict__ B,
    u16* __restrict__ A, u16* __restrict__ Bt)
{
    __shared__ float tile[64][65];
    const int bid = blockIdx.x;
    const int tid = threadIdx.x;

    if (bid < 2 * NPTS) {
        // ---- kstar ----
        const int n  = bid >> 1;
        const int k0 = ((bid & 1) * 256 + tid) * 8;   // 8 consecutive k per thread

        float xr[DDIM], il[DDIM];
#pragma unroll
        for (int d = 0; d < DDIM; ++d) {
            xr[d] = x[n * DDIM + d];
            il[d] = 1.0f / ls[d];
        }

        alignas(16) u16 res[8];
#pragma unroll
        for (int j = 0; j < 8; ++j) {
            const float4 g0 = *reinterpret_cast<const float4*>(g + (size_t)(k0 + j) * DDIM);
            const float4 g1 = *reinterpret_cast<const float4*>(g + (size_t)(k0 + j) * DDIM + 4);
            float s = fabsf(xr[0] - g0.x) * il[0] + fabsf(xr[1] - g0.y) * il[1]
                    + fabsf(xr[2] - g0.z) * il[2] + fabsf(xr[3] - g0.w) * il[3]
                    + fabsf(xr[4] - g1.x) * il[4] + fabsf(xr[5] - g1.y) * il[5]
                    + fabsf(xr[6] - g1.z) * il[6] + fabsf(xr[7] - g1.w) * il[7];
            res[j] = f2bf(__expf(-s));
        }
        *reinterpret_cast<uint4*>(A + (size_t)n * MGRD + k0) = *reinterpret_cast<const uint4*>(res);
    } else {
        // ---- transpose + convert (block-lower-triangular tiles only) ----
        const int id = bid - 2 * NPTS;
        const int bx = id & 63;          // m-tile
        const int by = id >> 6;          // k-tile
        if (by < (bx & ~1)) return;      // tile never read by triangular GEMM
        const int k0 = by * 64;
        const int m0 = bx * 64;

#pragma unroll
        for (int r = 0; r < 4; ++r) {
            int c   = r * 256 + tid;
            int row = c >> 4;
            int col = (c & 15) * 4;
            const float4 v = *reinterpret_cast<const float4*>(&B[(size_t)(k0 + row) * MGRD + m0 + col]);
            tile[row][col + 0] = v.x; tile[row][col + 1] = v.y;
            tile[row][col + 2] = v.z; tile[row][col + 3] = v.w;
        }
        __syncthreads();

#pragma unroll
        for (int r = 0; r < 2; ++r) {
            int c  = r * 256 + tid;
            int mr = c >> 3;
            int kc = (c & 7) * 8;
            alignas(16) u16 tmp[8];
#pragma unroll
            for (int j = 0; j < 8; ++j)
                tmp[j] = f2bf(tile[kc + j][mr]);
            *reinterpret_cast<uint4*>(&Bt[(size_t)(m0 + mr) * MGRD + k0 + kc]) =
                *reinterpret_cast<const uint4*>(tmp);
        }
    }
}

// ---------------- G: C[n][m] = sum_{k>=bm0} A[n][k] * Bt[m][k], bf16 MFMA, fp32 out --------
// m97 structure + XOR-swizzled LDS (conflict-free, verified R2) + reverse-K lockstep
// (L2 slice-sharing, FETCH 137 MB verified R3) + complementary-bm balance swizzle:
// dispatch->CU mapping has period 256 and 256 % 32 == 0, so an unswizzled (32,32) grid
// puts FOUR SAME-bm blocks on each CU (per-CU work 4*(64-2*bm) iters: 256 on bm=0 CUs,
// 4 on bm=31 CUs -- R3's triangular savings burned as idle CUs). Pairing bm <-> 31-bm
// across rounds makes every CU's 4 resident blocks total 2*66 = 132 iter-units.
__global__ __launch_bounds__(256, 3) void gemm_bt_kernel(
    const u16* __restrict__ A,    // [4096][4096] bf16 (n-major, k contiguous)
    const u16* __restrict__ Bt,   // [4096][4096] bf16 (m-major, k contiguous)
    float* __restrict__ C)        // [4096][4096] fp32
{
    __shared__ u16 sA[128 * 64] __attribute__((aligned(16)));
    __shared__ u16 sB[128 * 64] __attribute__((aligned(16)));

    const int tid   = threadIdx.x;
    const int lane  = tid & 63;
    const int w     = tid >> 6;
    const int wbase = w * 64;           // wave's staging chunk base within a round
    const int wm    = (w >> 1) * 64;    // wave n-offset in tile
    const int wn    = (w & 1) * 64;     // wave m-offset in tile

    // balance swizzle: l -> (bm, bn)
    const int l  = blockIdx.x;
    const int t  = l >> 8;              // 0..3: which resident "round" on the CU
    const int r_ = l & 255;
    const int b  = r_ & 31;
    const int bm = (t & 1) ? (31 - b) : b;
    const int bn = (r_ >> 5) + 8 * t;
    const int bn0 = bn * 128;
    const int bm0 = bm * 128;

    const int lrow  = lane & 15;
    const int lhi   = lane >> 4;        // 0..3
    const int r7    = lrow & 7;         // read-side swizzle key (row&7 == lrow&7 here)

    floatx4 acc[4][4];
#pragma unroll
    for (int i = 0; i < 4; ++i)
#pragma unroll
        for (int j = 0; j < 4; ++j)
            acc[i][j] = (floatx4)0.0f;

    for (int k0 = 4096 - 64; k0 >= bm0; k0 -= 64) {
        // Stage A-tile [128 n][64 k] and Bt-tile [128 m][64 k]. Slot c = r*256+tid maps to
        // (row = c>>3, swizzled 16B-chunk = c&7); the data placed there is global chunk
        // (c&7) ^ (row&7) -- LDS dest stays wave-order contiguous (global_load_lds
        // requirement); the *source* address carries the swizzle.
#pragma unroll
        for (int r = 0; r < 4; ++r) {
            int c   = r * 256 + tid;
            int row = c >> 3;
            int kc  = ((c ^ (c >> 3)) & 7) * 8;
            const u16* ga = A  + (size_t)(bn0 + row) * 4096 + k0 + kc;
            const u16* gb = Bt + (size_t)(bm0 + row) * 4096 + k0 + kc;
            __builtin_amdgcn_global_load_lds(
                (const __attribute__((address_space(1))) void*)ga,
                (__attribute__((address_space(3))) void*)(sA + (size_t)(r * 256 + wbase) * 8),
                16, 0, 0);
            __builtin_amdgcn_global_load_lds(
                (const __attribute__((address_space(1))) void*)gb,
                (__attribute__((address_space(3))) void*)(sB + (size_t)(r * 256 + wbase) * 8),
                16, 0, 0);
        }
        __syncthreads();

#pragma unroll
        for (int s = 0; s < 2; ++s) {
            const int sw = ((s * 4 + lhi) ^ r7) * 8;   // un-swizzled fragment chunk
            bf16x8 af[4], bfr[4];
#pragma unroll
            for (int i = 0; i < 4; ++i)
                af[i] = *reinterpret_cast<const bf16x8*>(
                    &sA[(size_t)(wm + i * 16 + lrow) * 64 + sw]);
#pragma unroll
            for (int j = 0; j < 4; ++j)
                bfr[j] = *reinterpret_cast<const bf16x8*>(
                    &sB[(size_t)(wn + j * 16 + lrow) * 64 + sw]);
#pragma unroll
            for (int i = 0; i < 4; ++i)
#pragma unroll
                for (int j = 0; j < 4; ++j)
                    acc[i][j] = __builtin_amdgcn_mfma_f32_16x16x32_bf16(
                        af[i], bfr[j], acc[i][j], 0, 0, 0);
        }
        __syncthreads();
    }

    // Epilogue: C/D layout col=lane&15 (m), row=(lane>>4)*4+reg (n)  [m89-verified]
#pragma unroll
    for (int i = 0; i < 4; ++i) {
        int rown = bn0 + wm + i * 16 + lhi * 4;
#pragma unroll
        for (int j = 0; j < 4; ++j) {
            int colm = bm0 + wn + j * 16 + lrow;
            float* cp = C + (size_t)rown * 4096 + colm;
#pragma unroll
            for (int rr = 0; rr < 4; ++rr)
                cp[(size_t)rr * 4096] = acc[i][j][rr];
        }
    }
}

extern "C" void kernel_launch(void* const* d_in, const int* in_sizes, int n_in,
                              void* d_out, int out_size, void* d_ws, size_t ws_size,
                              hipStream_t stream)
{
    const float* x    = (const float*)d_in[0];   // [4096,8]
    const float* grid = (const float*)d_in[1];   // [4096,8]
    const float* ci   = (const float*)d_in[2];   // [4096,4096]
    const float* ls   = (const float*)d_in[3];   // [8]
    float* out = (float*)d_out;                  // [4096,4096] fp32

    u16* wsA  = (u16*)d_ws;                            // k_star bf16, 33.5 MB
    u16* wsBt = (u16*)d_ws + (size_t)MGRD * MGRD;      // chol_inv^T bf16, 33.5 MB

    prep_kernel<<<dim3(2 * NPTS + 64 * 64), 256, 0, stream>>>(x, grid, ls, ci, wsA, wsBt);
    gemm_bt_kernel<<<dim3(1024), 256, 0, stream>>>(wsA, wsBt, out);
}

// Round 5
// 203.093 us; speedup vs baseline: 1.7205x; 1.2404x over previous
//
#include <hip/hip_runtime.h>
#include <cstdint>
#include <cstddef>

typedef unsigned short u16;
typedef __bf16 bf16x8 __attribute__((ext_vector_type(8)));
typedef float floatx4 __attribute__((ext_vector_type(4)));

#define NPTS 4096
#define MGRD 4096
#define DDIM 8

// round-to-nearest-even fp32 -> bf16
static __device__ __forceinline__ u16 f2bf(float f) {
    uint32_t u = __float_as_uint(f);
    u += 0x7fffu + ((u >> 16) & 1u);
    return (u16)(u >> 16);
}

// ---------------- Fused prep ----------------
// blocks 0..511:    kstar. Block = (n-group of 16) x (k-half of 2048). Each thread stages
//                   its 8 grid rows (64 VGPRs) ONCE, then loops 16 n-values reusing them.
//                   R4's version re-ran the 256B-lane-stride grid load for every (n-pair,k)
//                   block (8192 instances, 64 L1-line transactions per load inst, 536 MB L2
//                   demand); register residency cuts the instance count 32x.
// blocks 512..4607: tril transpose. Bt[m][k] = bf16(chol_inv[k][m]), only tiles the
//                   triangular GEMM reads (by >= bx&~1).
__global__ __launch_bounds__(256) void prep_kernel(
    const float* __restrict__ x, const float* __restrict__ g,
    const float* __restrict__ ls, const float* __restrict__ B,
    u16* __restrict__ A, u16* __restrict__ Bt)
{
    __shared__ float tile[64][65];
    const int bid = blockIdx.x;
    const int tid = threadIdx.x;

    if (bid < 512) {
        // ---- kstar ----
        const int kb = bid & 1;
        const int n0 = (bid >> 1) * 16;
        const int k0 = kb * 2048 + tid * 8;       // this thread's 8 grid rows

        float il[DDIM];
#pragma unroll
        for (int d = 0; d < DDIM; ++d) il[d] = 1.0f / ls[d];

        // stage 8 grid rows in registers (64 VGPRs)
        float4 g0[8], g1[8];
#pragma unroll
        for (int r = 0; r < 8; ++r) {
            g0[r] = *reinterpret_cast<const float4*>(g + (size_t)(k0 + r) * DDIM);
            g1[r] = *reinterpret_cast<const float4*>(g + (size_t)(k0 + r) * DDIM + 4);
        }

        for (int nn = 0; nn < 16; ++nn) {
            const int n = n0 + nn;
            const float4 x0 = *reinterpret_cast<const float4*>(x + (size_t)n * DDIM);
            const float4 x1 = *reinterpret_cast<const float4*>(x + (size_t)n * DDIM + 4);
            alignas(16) u16 res[8];
#pragma unroll
            for (int r = 0; r < 8; ++r) {
                float s = fabsf(x0.x - g0[r].x) * il[0] + fabsf(x0.y - g0[r].y) * il[1]
                        + fabsf(x0.z - g0[r].z) * il[2] + fabsf(x0.w - g0[r].w) * il[3]
                        + fabsf(x1.x - g1[r].x) * il[4] + fabsf(x1.y - g1[r].y) * il[5]
                        + fabsf(x1.z - g1[r].z) * il[6] + fabsf(x1.w - g1[r].w) * il[7];
                res[r] = f2bf(__expf(-s));
            }
            *reinterpret_cast<uint4*>(A + (size_t)n * MGRD + k0) =
                *reinterpret_cast<const uint4*>(res);
        }
    } else {
        // ---- transpose + convert (block-lower-triangular tiles only) ----
        const int id = bid - 512;
        const int bx = id & 63;          // m-tile
        const int by = id >> 6;          // k-tile
        if (by < (bx & ~1)) return;      // tile never read by triangular GEMM
        const int k0 = by * 64;
        const int m0 = bx * 64;

#pragma unroll
        for (int r = 0; r < 4; ++r) {
            int c   = r * 256 + tid;
            int row = c >> 4;
            int col = (c & 15) * 4;
            const float4 v = *reinterpret_cast<const float4*>(&B[(size_t)(k0 + row) * MGRD + m0 + col]);
            tile[row][col + 0] = v.x; tile[row][col + 1] = v.y;
            tile[row][col + 2] = v.z; tile[row][col + 3] = v.w;
        }
        __syncthreads();

#pragma unroll
        for (int r = 0; r < 2; ++r) {
            int c  = r * 256 + tid;
            int mr = c >> 3;
            int kc = (c & 7) * 8;
            alignas(16) u16 tmp[8];
#pragma unroll
            for (int j = 0; j < 8; ++j)
                tmp[j] = f2bf(tile[kc + j][mr]);
            *reinterpret_cast<uint4*>(&Bt[(size_t)(m0 + mr) * MGRD + k0 + kc]) =
                *reinterpret_cast<const uint4*>(tmp);
        }
    }
}

// ---------------- G: C[n][m] = sum_{k>=bm0} A[n][k] * Bt[m][k], bf16 MFMA, fp32 out --------
// m97 structure + XOR-swizzled LDS (conflict-free, verified R2) + reverse-K lockstep
// (L2 slice-sharing, verified R3) + complementary-bm balance swizzle (dispatch->CU period
// 256 == 0 mod 32, pairing bm <-> 31-bm gives every CU 132 iter-units; verified R4:
// 113.5 -> 86 us). Effective 822 TF on triangular work ~= 94% of m97-structure plateau.
__global__ __launch_bounds__(256, 3) void gemm_bt_kernel(
    const u16* __restrict__ A,    // [4096][4096] bf16 (n-major, k contiguous)
    const u16* __restrict__ Bt,   // [4096][4096] bf16 (m-major, k contiguous)
    float* __restrict__ C)        // [4096][4096] fp32
{
    __shared__ u16 sA[128 * 64] __attribute__((aligned(16)));
    __shared__ u16 sB[128 * 64] __attribute__((aligned(16)));

    const int tid   = threadIdx.x;
    const int lane  = tid & 63;
    const int w     = tid >> 6;
    const int wbase = w * 64;           // wave's staging chunk base within a round
    const int wm    = (w >> 1) * 64;    // wave n-offset in tile
    const int wn    = (w & 1) * 64;     // wave m-offset in tile

    // balance swizzle: l -> (bm, bn)
    const int l  = blockIdx.x;
    const int t  = l >> 8;              // 0..3: which resident "round" on the CU
    const int r_ = l & 255;
    const int b  = r_ & 31;
    const int bm = (t & 1) ? (31 - b) : b;
    const int bn = (r_ >> 5) + 8 * t;
    const int bn0 = bn * 128;
    const int bm0 = bm * 128;

    const int lrow  = lane & 15;
    const int lhi   = lane >> 4;        // 0..3
    const int r7    = lrow & 7;         // read-side swizzle key (row&7 == lrow&7 here)

    floatx4 acc[4][4];
#pragma unroll
    for (int i = 0; i < 4; ++i)
#pragma unroll
        for (int j = 0; j < 4; ++j)
            acc[i][j] = (floatx4)0.0f;

    for (int k0 = 4096 - 64; k0 >= bm0; k0 -= 64) {
        // Stage A-tile [128 n][64 k] and Bt-tile [128 m][64 k]. Slot c = r*256+tid maps to
        // (row = c>>3, swizzled 16B-chunk = c&7); the data placed there is global chunk
        // (c&7) ^ (row&7) -- LDS dest stays wave-order contiguous (global_load_lds
        // requirement); the *source* address carries the swizzle.
#pragma unroll
        for (int r = 0; r < 4; ++r) {
            int c   = r * 256 + tid;
            int row = c >> 3;
            int kc  = ((c ^ (c >> 3)) & 7) * 8;
            const u16* ga = A  + (size_t)(bn0 + row) * 4096 + k0 + kc;
            const u16* gb = Bt + (size_t)(bm0 + row) * 4096 + k0 + kc;
            __builtin_amdgcn_global_load_lds(
                (const __attribute__((address_space(1))) void*)ga,
                (__attribute__((address_space(3))) void*)(sA + (size_t)(r * 256 + wbase) * 8),
                16, 0, 0);
            __builtin_amdgcn_global_load_lds(
                (const __attribute__((address_space(1))) void*)gb,
                (__attribute__((address_space(3))) void*)(sB + (size_t)(r * 256 + wbase) * 8),
                16, 0, 0);
        }
        __syncthreads();

#pragma unroll
        for (int s = 0; s < 2; ++s) {
            const int sw = ((s * 4 + lhi) ^ r7) * 8;   // un-swizzled fragment chunk
            bf16x8 af[4], bfr[4];
#pragma unroll
            for (int i = 0; i < 4; ++i)
                af[i] = *reinterpret_cast<const bf16x8*>(
                    &sA[(size_t)(wm + i * 16 + lrow) * 64 + sw]);
#pragma unroll
            for (int j = 0; j < 4; ++j)
                bfr[j] = *reinterpret_cast<const bf16x8*>(
                    &sB[(size_t)(wn + j * 16 + lrow) * 64 + sw]);
#pragma unroll
            for (int i = 0; i < 4; ++i)
#pragma unroll
                for (int j = 0; j < 4; ++j)
                    acc[i][j] = __builtin_amdgcn_mfma_f32_16x16x32_bf16(
                        af[i], bfr[j], acc[i][j], 0, 0, 0);
        }
        __syncthreads();
    }

    // Epilogue: C/D layout col=lane&15 (m), row=(lane>>4)*4+reg (n)  [m89-verified]
#pragma unroll
    for (int i = 0; i < 4; ++i) {
        int rown = bn0 + wm + i * 16 + lhi * 4;
#pragma unroll
        for (int j = 0; j < 4; ++j) {
            int colm = bm0 + wn + j * 16 + lrow;
            float* cp = C + (size_t)rown * 4096 + colm;
#pragma unroll
            for (int rr = 0; rr < 4; ++rr)
                cp[(size_t)rr * 4096] = acc[i][j][rr];
        }
    }
}

extern "C" void kernel_launch(void* const* d_in, const int* in_sizes, int n_in,
                              void* d_out, int out_size, void* d_ws, size_t ws_size,
                              hipStream_t stream)
{
    const float* x    = (const float*)d_in[0];   // [4096,8]
    const float* grid = (const float*)d_in[1];   // [4096,8]
    const float* ci   = (const float*)d_in[2];   // [4096,4096]
    const float* ls   = (const float*)d_in[3];   // [8]
    float* out = (float*)d_out;                  // [4096,4096] fp32

    u16* wsA  = (u16*)d_ws;                            // k_star bf16, 33.5 MB
    u16* wsBt = (u16*)d_ws + (size_t)MGRD * MGRD;      // chol_inv^T bf16, 33.5 MB

    prep_kernel<<<dim3(512 + 64 * 64), 256, 0, stream>>>(x, grid, ls, ci, wsA, wsBt);
    gemm_bt_kernel<<<dim3(1024), 256, 0, stream>>>(wsA, wsBt, out);
}